// Round 13
// baseline (572.342 us; speedup 1.0000x reference)
//
#include <hip/hip_runtime.h>
#include <hip/hip_fp16.h>
#include <cfloat>
#include <cmath>

constexpr int NB = 8;
constexpr int NP = 2048;
constexpr int NK = 11;   // Taylor terms k=0..10; err <= s^11/11! (s ~ 0.3) ~ 1e-11

typedef __attribute__((ext_vector_type(4))) float f32x4;
typedef __attribute__((ext_vector_type(8))) short bf16x8;
#define MFMA16(a, b, c) __builtin_amdgcn_mfma_f32_16x16x32_bf16(a, b, c, 0, 0, 0)

__device__ inline ushort f2bf(float f) {   // round-to-nearest-even f32 -> bf16
  union { float f; unsigned u; } v; v.f = f;
  unsigned r = v.u + 0x7FFFu + ((v.u >> 16) & 1u);
  return (ushort)(r >> 16);
}
__device__ inline unsigned pk2bf(float a, float b) {
  return (unsigned)f2bf(a) | ((unsigned)f2bf(b) << 16);
}

// Full 64-lane i32 sum via VALU DPP; total in lane 63, returned via readlane.
__device__ inline int dpp_wave_sum_i32(int c) {
  c += __builtin_amdgcn_update_dpp(0, c, 0x111, 0xf, 0xf, true);  // row_shr:1
  c += __builtin_amdgcn_update_dpp(0, c, 0x112, 0xf, 0xf, true);  // row_shr:2
  c += __builtin_amdgcn_update_dpp(0, c, 0x114, 0xf, 0xf, true);  // row_shr:4
  c += __builtin_amdgcn_update_dpp(0, c, 0x118, 0xf, 0xf, true);  // row_shr:8
  c += __builtin_amdgcn_update_dpp(0, c, 0x142, 0xf, 0xf, true);  // row_bcast:15
  c += __builtin_amdgcn_update_dpp(0, c, 0x143, 0xf, 0xf, true);  // row_bcast:31
  return __builtin_amdgcn_readlane(c, 63);
}

// ---------- prep: normalize x -> xn ; transpose x -> xt [B,3,N] ----------
__global__ void k_prep(const float* __restrict__ x, float* __restrict__ xn, float* __restrict__ xt) {
  int i = blockIdx.x * blockDim.x + threadIdx.x;
  if (i >= NB * NP) return;
  int b = i >> 11, n = i & (NP - 1);
  float a0 = x[i * 3 + 0], a1 = x[i * 3 + 1], a2 = x[i * 3 + 2];
  float rn = rsqrtf(a0 * a0 + a1 * a1 + a2 * a2);
  xn[i * 3 + 0] = a0 * rn; xn[i * 3 + 1] = a1 * rn; xn[i * 3 + 2] = a2 * rn;
  float* xb = xt + (size_t)b * 3 * NP;
  xb[0 * NP + n] = a0; xb[1 * NP + n] = a1; xb[2 * NP + n] = a2;
}

__global__ void k_zero1(float* p) { if (threadIdx.x == 0) p[0] = 0.f; }

// ---------- density: fp16-quantized dist in LDS, integer-domain select ----------
// Block = 512 threads = 8 waves = 8 rows. LDS: SoA points (24 KB) + u16
// dist[8][2048] (32 KB) = 56 KB -> 2 blocks/CU (4 waves/SIMD). Positive halfs
// order as u16 ints, so top-32 selection runs as an integer search:
// 8 quaternary + 2 binary passes reach interval=1 (EXACT in fp16 domain;
// boundary ties pad with the exact boundary value).
__global__ __launch_bounds__(512) void k_density(const float* __restrict__ xn,
                                                 float* __restrict__ inv,
                                                 int* __restrict__ maxinv) {
  __shared__ float sx[NP], sy[NP], sz[NP];
  __shared__ ushort dq[8][NP];
  int t = threadIdx.x;
  int w = t >> 6, lane = t & 63;
  int row0 = blockIdx.x * 8;
  int b = row0 >> 11;                       // 256 blocks per batch
  const float4* xb4 = (const float4*)(xn + (size_t)b * NP * 3);
  {  // thread t stages points 4t..4t+3 (3 coalesced float4 loads)
    float4 a = xb4[t * 3 + 0], c4 = xb4[t * 3 + 1], e4 = xb4[t * 3 + 2];
    int p = t * 4;
    sx[p + 0] = a.x;  sy[p + 0] = a.y;  sz[p + 0] = a.z;
    sx[p + 1] = a.w;  sy[p + 1] = c4.x; sz[p + 1] = c4.y;
    sx[p + 2] = c4.z; sy[p + 2] = c4.w; sz[p + 2] = e4.x;
    sx[p + 3] = e4.y; sy[p + 3] = e4.z; sz[p + 3] = e4.w;
  }
  __syncthreads();
  int row = row0 + w;
  int n = row & (NP - 1);
  float px = sx[n], py = sy[n], pz = sz[n];   // broadcast read
  ushort* dr = dq[w];
  int mni = 0xFFFF, mxi = 0;
  #pragma unroll
  for (int k = 0; k < 32; ++k) {
    int m = lane + (k << 6);
    float v = fmaxf(1.0f - (px * sx[m] + py * sy[m] + pz * sz[m]), 0.0f);  // clamp: keep sign bit clear
    ushort u = __half_as_ushort(__float2half(v));
    dr[m] = u;
    int ui = (int)u;
    mni = min(mni, ui); mxi = max(mxi, ui);
  }
  // lo = row min; hi = (min over lanes of per-lane max)+1 -> cnt(<hi) >= 32
  #pragma unroll
  for (int off = 32; off; off >>= 1) {
    mni = min(mni, __shfl_xor(mni, off));
    mxi = min(mxi, __shfl_xor(mxi, off));   // MIN of per-lane maxes
  }
  int lo = mni, hi = mxi + 1;
  #pragma unroll
  for (int it = 0; it < 8; ++it) {          // quaternary: 3 thresholds/pass
    int d = hi - lo;
    int t1 = lo + (d >> 2), t2 = lo + (d >> 1), t3 = lo + d - (d >> 2);
    int c12 = 0, c3 = 0;
    #pragma unroll
    for (int k = 0; k < 32; ++k) {
      int u = (int)dr[lane + (k << 6)];
      c12 += (u < t1 ? 1 : 0) + (u < t2 ? (1 << 12) : 0);
      c3  += (u < t3 ? 1 : 0);
    }
    c12 = dpp_wave_sum_i32(c12);
    c3  = dpp_wave_sum_i32(c3);
    int c1 = c12 & 0xFFF, c2 = c12 >> 12;
    if (c3 <= 32)      { lo = t3; }
    else if (c2 <= 32) { lo = t2; hi = t3; }
    else if (c1 <= 32) { lo = t1; hi = t2; }
    else               { hi = t1; }
  }
  #pragma unroll
  for (int it = 0; it < 2; ++it) {          // binary cleanup to interval = 1
    int tt = lo + ((hi - lo) >> 1);
    int c = 0;
    #pragma unroll
    for (int k = 0; k < 32; ++k) c += ((int)dr[lane + (k << 6)] < tt) ? 1 : 0;
    c = dpp_wave_sum_i32(c);
    if (c <= 32) lo = tt; else hi = tt;
  }
  float s = 0.f; int c = 0;
  #pragma unroll
  for (int k = 0; k < 32; ++k) {
    int u = (int)dr[lane + (k << 6)];
    bool p = u < lo;
    s += p ? __half2float(__ushort_as_half((ushort)u)) : 0.f;
    c += p ? 1 : 0;
  }
  int ctot = dpp_wave_sum_i32(c);
  #pragma unroll
  for (int off = 32; off; off >>= 1) s += __shfl_xor(s, off);
  // remaining picks all equal the boundary value lo (exact in fp16 domain)
  float sum = s + (float)(32 - ctot) * __half2float(__ushort_as_half((ushort)lo));
  if (lane == 0) {
    float iv = 32.0f / sum;
    inv[row] = iv;
    atomicMax(maxinv, __float_as_int(iv));
  }
}

__global__ void k_scale(float* __restrict__ dens, const float* __restrict__ maxinv) {
  int i = blockIdx.x * 256 + threadIdx.x;
  if (i < NB * NP) dens[i] *= (1.0f / maxinv[0]);
}

// ---------- coef[k] = s^k / k!,  s = sum(wqk^2) ----------
__global__ __launch_bounds__(64) void k_coef(const float* __restrict__ wqk, int D,
                                             float* __restrict__ coef) {
  int lane = threadIdx.x;
  float v = 0.f;
  for (int i = lane; i < D; i += 64) v += wqk[i] * wqk[i];
  #pragma unroll
  for (int off = 32; off; off >>= 1) v += __shfl_xor(v, off);
  if (lane == 0) {
    float c = 1.f;
    coef[0] = 1.f;
    for (int k = 1; k < NK; ++k) { c *= v / (float)k; coef[k] = c; }
  }
}

// ---------- per-batch: S_k -> rinv -> T_k -> cinv (all in one block) ----------
__global__ __launch_bounds__(256) void k_attn_small(const float* __restrict__ dens,
                                                    const float* __restrict__ coef,
                                                    float* __restrict__ rinv,
                                                    float* __restrict__ cinv) {
  int b = blockIdx.x, t = threadIdx.x, w = t >> 6, lane = t & 63;
  const float* db = dens + b * NP;
  float d[8], r[8];
  *(float4*)&d[0] = *(const float4*)(db + t * 8);
  *(float4*)&d[4] = *(const float4*)(db + t * 8 + 4);
  __shared__ float part[NK][4];
  float q[NK];
  // S_k = sum d^k
  {
    float acc[NK];
    #pragma unroll
    for (int k = 0; k < NK; ++k) acc[k] = 0.f;
    #pragma unroll
    for (int e = 0; e < 8; ++e) {
      float p = 1.f;
      #pragma unroll
      for (int k = 0; k < NK; ++k) { acc[k] += p; p *= d[e]; }
    }
    #pragma unroll
    for (int k = 0; k < NK; ++k) {
      float a = acc[k];
      #pragma unroll
      for (int off = 32; off; off >>= 1) a += __shfl_xor(a, off);
      if (lane == 0) part[k][w] = a;
    }
    __syncthreads();
    #pragma unroll
    for (int k = 0; k < NK; ++k)
      q[k] = coef[k] * ((part[k][0] + part[k][1]) + (part[k][2] + part[k][3]));
    __syncthreads();
  }
  // rinv[n] = 1 / sum_k q_k d^k
  #pragma unroll
  for (int e = 0; e < 8; ++e) {
    float poly = q[NK - 1];
    #pragma unroll
    for (int k = NK - 2; k >= 0; --k) poly = poly * d[e] + q[k];
    r[e] = 1.0f / poly;
  }
  *(float4*)(rinv + b * NP + t * 8)     = *(float4*)&r[0];
  *(float4*)(rinv + b * NP + t * 8 + 4) = *(float4*)&r[4];
  // T_k = sum rinv d^k
  {
    float acc[NK];
    #pragma unroll
    for (int k = 0; k < NK; ++k) acc[k] = 0.f;
    #pragma unroll
    for (int e = 0; e < 8; ++e) {
      float p = r[e];
      #pragma unroll
      for (int k = 0; k < NK; ++k) { acc[k] += p; p *= d[e]; }
    }
    #pragma unroll
    for (int k = 0; k < NK; ++k) {
      float a = acc[k];
      #pragma unroll
      for (int off = 32; off; off >>= 1) a += __shfl_xor(a, off);
      if (lane == 0) part[k][w] = a;
    }
    __syncthreads();
    #pragma unroll
    for (int k = 0; k < NK; ++k)
      q[k] = coef[k] * ((part[k][0] + part[k][1]) + (part[k][2] + part[k][3]));
  }
  // cinv[m] = 1 / (1e-9 + sum_k q_k d^k)
  #pragma unroll
  for (int e = 0; e < 8; ++e) {
    float poly = q[NK - 1];
    #pragma unroll
    for (int k = NK - 2; k >= 0; --k) poly = poly * d[e] + q[k];
    r[e] = 1.0f / (poly + 1e-9f);
  }
  *(float4*)(cinv + b * NP + t * 8)     = *(float4*)&r[0];
  *(float4*)(cinv + b * NP + t * 8 + 4) = *(float4*)&r[4];
}

// ---------- fused x_r: one block per (b,c) row ----------
// P_k = sum_n H[c][n] rinv[n] d^k ; U[c][m] = H[c][m] - cinv[m]*sum_k coef_k P_k d^k
__global__ __launch_bounds__(256) void k_xrP(const float* __restrict__ H, float* __restrict__ U,
                                             const float* __restrict__ dens,
                                             const float* __restrict__ rinv,
                                             const float* __restrict__ cinv,
                                             const float* __restrict__ coef, int C) {
  int b = blockIdx.y, c = blockIdx.x, t = threadIdx.x, w = t >> 6, lane = t & 63;
  const float* Hc = H + ((size_t)b * C + c) * NP;
  float* Uc = U + ((size_t)b * C + c) * NP;
  const float* db = dens + b * NP;
  const float* rb = rinv + b * NP;
  const float* cb = cinv + b * NP;
  float h[8], d[8], r[8], cv[8];
  *(float4*)&h[0] = *(const float4*)(Hc + t * 8);
  *(float4*)&h[4] = *(const float4*)(Hc + t * 8 + 4);
  *(float4*)&d[0] = *(const float4*)(db + t * 8);
  *(float4*)&d[4] = *(const float4*)(db + t * 8 + 4);
  *(float4*)&r[0] = *(const float4*)(rb + t * 8);
  *(float4*)&r[4] = *(const float4*)(rb + t * 8 + 4);
  *(float4*)&cv[0] = *(const float4*)(cb + t * 8);
  *(float4*)&cv[4] = *(const float4*)(cb + t * 8 + 4);
  float acc[NK];
  #pragma unroll
  for (int k = 0; k < NK; ++k) acc[k] = 0.f;
  #pragma unroll
  for (int e = 0; e < 8; ++e) {
    float p = h[e] * r[e];
    #pragma unroll
    for (int k = 0; k < NK; ++k) { acc[k] += p; p *= d[e]; }
  }
  __shared__ float part[NK][4];
  #pragma unroll
  for (int k = 0; k < NK; ++k) {
    float a = acc[k];
    #pragma unroll
    for (int off = 32; off; off >>= 1) a += __shfl_xor(a, off);
    if (lane == 0) part[k][w] = a;
  }
  __syncthreads();
  float q[NK];
  #pragma unroll
  for (int k = 0; k < NK; ++k)
    q[k] = coef[k] * ((part[k][0] + part[k][1]) + (part[k][2] + part[k][3]));
  float u[8];
  #pragma unroll
  for (int e = 0; e < 8; ++e) {
    float poly = q[NK - 1];
    #pragma unroll
    for (int k = NK - 2; k >= 0; --k) poly = poly * d[e] + q[k];
    u[e] = h[e] - cv[e] * poly;
  }
  *(float4*)(Uc + t * 8)     = *(float4*)&u[0];
  *(float4*)(Uc + t * 8 + 4) = *(float4*)&u[4];
}

// ---------- conv1x1 via bf16 MFMA ----------
constexpr int LDA = 72;  // bf16 units per LDS row (64 + 8 pad)

__global__ __launch_bounds__(256) void k_gemm_mfma(const float* __restrict__ W,
                                                   const float* __restrict__ IN,
                                                   const float* __restrict__ bias,
                                                   float* __restrict__ OUT,
                                                   int Cin, int Cout) {
  int b = blockIdx.z, n0 = blockIdx.x * 128, o0 = blockIdx.y * 128;
  int tid = threadIdx.x, lane = tid & 63, w = tid >> 6;
  int wr = w >> 1, wc = w & 1;
  const float* Ib = IN + (size_t)b * Cin * NP;
  float* Ob = OUT + (size_t)b * Cout * NP;
  __shared__ ushort Asm[128 * LDA];
  __shared__ ushort Bsm[128 * LDA];
  f32x4 acc[4][4];
  #pragma unroll
  for (int i = 0; i < 4; ++i)
    #pragma unroll
    for (int j = 0; j < 4; ++j) acc[i][j] = (f32x4)(0.0f);

  int row = tid >> 1, half = tid & 1;
  int csub = tid & 63, q = tid >> 6;
  for (int cc0 = 0; cc0 < Cin; cc0 += 64) {
    __syncthreads();
    {   // A: rows=o (128), cols=c' (64) from W
      const float* src = W + (size_t)(o0 + row) * Cin + cc0 + half * 32;
      unsigned* dst = (unsigned*)(Asm + row * LDA + half * 32);
      #pragma unroll
      for (int i = 0; i < 8; ++i) {
        float4 v = *(const float4*)(src + i * 4);
        dst[i * 2 + 0] = pk2bf(v.x, v.y);
        dst[i * 2 + 1] = pk2bf(v.z, v.w);
      }
      // B: rows=n' (128), cols=c' (64) — transpose of IN[c][n]
      const float* isrc = Ib + (size_t)(cc0 + csub) * NP + n0 + q * 32;
      #pragma unroll
      for (int i = 0; i < 8; ++i) {
        float4 v = *(const float4*)(isrc + i * 4);
        ushort* bd = Bsm + (q * 32 + i * 4) * LDA + csub;
        bd[0]       = f2bf(v.x);
        bd[LDA]     = f2bf(v.y);
        bd[2 * LDA] = f2bf(v.z);
        bd[3 * LDA] = f2bf(v.w);
      }
    }
    __syncthreads();
    #pragma unroll
    for (int kk = 0; kk < 64; kk += 32) {
      bf16x8 af[4], bfr[4];
      #pragma unroll
      for (int i = 0; i < 4; ++i) {
        af[i]  = *(const bf16x8*)(Asm + (wr * 64 + i * 16 + (lane & 15)) * LDA + kk + (lane >> 4) * 8);
        bfr[i] = *(const bf16x8*)(Bsm + (wc * 64 + i * 16 + (lane & 15)) * LDA + kk + (lane >> 4) * 8);
      }
      #pragma unroll
      for (int i = 0; i < 4; ++i)
        #pragma unroll
        for (int j = 0; j < 4; ++j)
          acc[i][j] = MFMA16(af[i], bfr[j], acc[i][j]);
    }
  }
  #pragma unroll
  for (int i = 0; i < 4; ++i) {
    #pragma unroll
    for (int r = 0; r < 4; ++r) {
      int o = o0 + wr * 64 + i * 16 + (lane >> 4) * 4 + r;
      float bv = bias[o];
      #pragma unroll
      for (int j = 0; j < 4; ++j) {
        int n = n0 + wc * 64 + j * 16 + (lane & 15);
        Ob[(size_t)o * NP + n] = acc[i][j][r] + bv;
      }
    }
  }
}

// ---------- fp32 GEMM (conv1 only, Cin=3) ----------
__global__ __launch_bounds__(256) void k_gemm(const float* __restrict__ W,
                                              const float* __restrict__ IN,
                                              const float* __restrict__ bias,
                                              float* __restrict__ OUT,
                                              int Cin, int Cout) {
  int b = blockIdx.z;
  int n0 = blockIdx.x * 64;
  int o0 = blockIdx.y * 64;
  int tid = threadIdx.x;
  int tx = tid & 15, ty = tid >> 4;
  const float* Ib = IN + (size_t)b * Cin * NP;
  float* Ob = OUT + (size_t)b * Cout * NP;
  __shared__ float Wt[64][65];
  __shared__ float It[64][65];
  float acc[4][4] = {};
  for (int c0 = 0; c0 < Cin; c0 += 64) {
    __syncthreads();
    {
      int ci = tid & 63, ob4 = tid >> 6;
      bool cv = (c0 + ci) < Cin;
      #pragma unroll
      for (int k = 0; k < 16; ++k) {
        int oi = ob4 + (k << 2);
        Wt[ci][oi] = cv ? W[(size_t)(o0 + oi) * Cin + c0 + ci] : 0.f;
      }
      int ni = tid & 63, cb4 = tid >> 6;
      #pragma unroll
      for (int k = 0; k < 16; ++k) {
        int ci2 = cb4 + (k << 2);
        It[ci2][ni] = (c0 + ci2) < Cin ? Ib[(size_t)(c0 + ci2) * NP + n0 + ni] : 0.f;
      }
    }
    __syncthreads();
    #pragma unroll 4
    for (int ci = 0; ci < 64; ++ci) {
      float a0 = Wt[ci][ty * 4 + 0], a1 = Wt[ci][ty * 4 + 1], a2 = Wt[ci][ty * 4 + 2], a3 = Wt[ci][ty * 4 + 3];
      float b0 = It[ci][tx * 4 + 0], b1 = It[ci][tx * 4 + 1], b2 = It[ci][tx * 4 + 2], b3 = It[ci][tx * 4 + 3];
      acc[0][0] += a0 * b0; acc[0][1] += a0 * b1; acc[0][2] += a0 * b2; acc[0][3] += a0 * b3;
      acc[1][0] += a1 * b0; acc[1][1] += a1 * b1; acc[1][2] += a1 * b2; acc[1][3] += a1 * b3;
      acc[2][0] += a2 * b0; acc[2][1] += a2 * b1; acc[2][2] += a2 * b2; acc[2][3] += a2 * b3;
      acc[3][0] += a3 * b0; acc[3][1] += a3 * b1; acc[3][2] += a3 * b2; acc[3][3] += a3 * b3;
    }
  }
  #pragma unroll
  for (int i = 0; i < 4; ++i) {
    int o = o0 + ty * 4 + i;
    float bv = bias[o];
    #pragma unroll
    for (int j = 0; j < 4; ++j) {
      int n = n0 + tx * 4 + j;
      Ob[(size_t)o * NP + n] = acc[i][j] + bv;
    }
  }
}

// ---------- fused BN: stats + apply, values held in registers ----------
__global__ __launch_bounds__(256) void k_bn(const float* __restrict__ T, float* __restrict__ H,
                                            int C, int relu, int acc) {
  int c = blockIdx.x, t = threadIdx.x, w = t >> 6, lane = t & 63;
  float4 v[16];
  float s = 0.f, s2 = 0.f;
  #pragma unroll
  for (int b = 0; b < NB; ++b) {
    const float4* p = (const float4*)(T + ((size_t)b * C + c) * NP);
    #pragma unroll
    for (int i = 0; i < 2; ++i) {
      float4 x = p[t + i * 256];
      v[b * 2 + i] = x;
      s += (x.x + x.y) + (x.z + x.w);
      s2 += (x.x * x.x + x.y * x.y) + (x.z * x.z + x.w * x.w);
    }
  }
  #pragma unroll
  for (int off = 32; off; off >>= 1) { s += __shfl_xor(s, off); s2 += __shfl_xor(s2, off); }
  __shared__ float ps[4], ps2[4];
  if (lane == 0) { ps[w] = s; ps2[w] = s2; }
  __syncthreads();
  float ts = (ps[0] + ps[1]) + (ps[2] + ps[3]);
  float ts2 = (ps2[0] + ps2[1]) + (ps2[2] + ps2[3]);
  float m = ts * (1.0f / (NB * NP));
  float var = ts2 * (1.0f / (NB * NP)) - m * m;
  float is = rsqrtf(var + 1e-5f);
  #pragma unroll
  for (int b = 0; b < NB; ++b) {
    float4* hp = (float4*)(H + ((size_t)b * C + c) * NP);
    #pragma unroll
    for (int i = 0; i < 2; ++i) {
      float4 x = v[b * 2 + i];
      x.x = (x.x - m) * is; x.y = (x.y - m) * is; x.z = (x.z - m) * is; x.w = (x.w - m) * is;
      if (relu) {
        x.x = fmaxf(x.x, 0.f); x.y = fmaxf(x.y, 0.f); x.z = fmaxf(x.z, 0.f); x.w = fmaxf(x.w, 0.f);
      }
      if (acc) {
        float4 h = hp[t + i * 256];
        x.x += h.x; x.y += h.y; x.z += h.z; x.w += h.w;
      }
      hp[t + i * 256] = x;
    }
  }
}

// ---------- global max pool over N ----------
__global__ __launch_bounds__(64) void k_maxpool(const float* __restrict__ H, float* __restrict__ g) {
  int bf = blockIdx.x;
  const float* p = H + (size_t)bf * NP;
  int lane = threadIdx.x;
  float mx = -FLT_MAX;
  for (int n = lane; n < NP; n += 64) mx = fmaxf(mx, p[n]);
  #pragma unroll
  for (int off = 32; off > 0; off >>= 1) mx = fmaxf(mx, __shfl_xor(mx, off));
  if (lane == 0) g[bf] = mx;
}

// ---------- MLP head ----------
__global__ __launch_bounds__(256) void k_head(const float* __restrict__ g,
    const float* __restrict__ f1mw, const float* __restrict__ f1mb,
    const float* __restrict__ f2mw, const float* __restrict__ f2mb,
    const float* __restrict__ f3mw, const float* __restrict__ f3mb,
    const float* __restrict__ f1vw, const float* __restrict__ f1vb,
    const float* __restrict__ f2vw, const float* __restrict__ f2vb,
    const float* __restrict__ f3vw, const float* __restrict__ f3vb,
    float* __restrict__ out) {
  bool vpath = (blockIdx.x == 1);
  const float* w1 = vpath ? f1vw : f1mw;
  const float* c1 = vpath ? f1vb : f1mb;
  const float* w2 = vpath ? f2vw : f2mw;
  const float* c2 = vpath ? f2vb : f2mb;
  __shared__ float gg[NB * 512];
  __shared__ float a1[NB * 256];
  __shared__ float a2[NB * 128];
  __shared__ float zz[NB * 128];
  __shared__ float nrm[NB];
  int t = threadIdx.x;
  for (int i = t; i < NB * 512; i += 256) gg[i] = g[i];
  __syncthreads();
  float o[NB];
  {
    #pragma unroll
    for (int b = 0; b < NB; ++b) o[b] = c1[t];
    const float* wr = w1 + (size_t)t * 512;
    for (int j = 0; j < 512; ++j) {
      float w = wr[j];
      #pragma unroll
      for (int b = 0; b < NB; ++b) o[b] += gg[b * 512 + j] * w;
    }
    float mean = 0.f;
    #pragma unroll
    for (int b = 0; b < NB; ++b) mean += o[b];
    mean *= (1.0f / NB);
    float var = 0.f;
    #pragma unroll
    for (int b = 0; b < NB; ++b) { float d = o[b] - mean; var += d * d; }
    var *= (1.0f / NB);
    float is = rsqrtf(var + 1e-5f);
    #pragma unroll
    for (int b = 0; b < NB; ++b) a1[b * 256 + t] = fmaxf((o[b] - mean) * is, 0.f);
  }
  __syncthreads();
  if (t < 128) {
    #pragma unroll
    for (int b = 0; b < NB; ++b) o[b] = c2[t];
    const float* wr = w2 + (size_t)t * 256;
    for (int j = 0; j < 256; ++j) {
      float w = wr[j];
      #pragma unroll
      for (int b = 0; b < NB; ++b) o[b] += a1[b * 256 + j] * w;
    }
    float mean = 0.f;
    #pragma unroll
    for (int b = 0; b < NB; ++b) mean += o[b];
    mean *= (1.0f / NB);
    float var = 0.f;
    #pragma unroll
    for (int b = 0; b < NB; ++b) { float d = o[b] - mean; var += d * d; }
    var *= (1.0f / NB);
    float is = rsqrtf(var + 1e-5f);
    #pragma unroll
    for (int b = 0; b < NB; ++b) a2[b * 128 + t] = fmaxf((o[b] - mean) * is, 0.f);
  }
  __syncthreads();
  if (!vpath) {
    if (t < 128) {
      const float* wr = f3mw + (size_t)t * 128;
      for (int b = 0; b < NB; ++b) {
        float s = f3mb[t];
        for (int j = 0; j < 128; ++j) s += a2[b * 128 + j] * wr[j];
        zz[b * 128 + t] = s;
      }
    }
    __syncthreads();
    if (t < NB) {
      float s = 0.f;
      for (int j = 0; j < 128; ++j) { float v = zz[t * 128 + j]; s += v * v; }
      nrm[t] = sqrtf(s);
    }
    __syncthreads();
    if (t < 128) {
      for (int b = 0; b < NB; ++b) out[b * 128 + t] = zz[b * 128 + t] / nrm[b];
    }
  } else {
    if (t < NB) {
      float s = f3vb[0];
      for (int j = 0; j < 128; ++j) s += a2[t * 128 + j] * f3vw[j];
      float sp = (s > 20.f) ? s : log1pf(expf(s));
      out[NB * 128 + t] = sp + 1.0f;
    }
  }
}

extern "C" void kernel_launch(void* const* d_in, const int* in_sizes, int n_in,
                              void* d_out, int out_size, void* d_ws, size_t ws_size,
                              hipStream_t stream) {
  const float* x  = (const float*)d_in[0];
  const float* w1 = (const float*)d_in[1];
  const float* b1 = (const float*)d_in[2];
  const float* w2 = (const float*)d_in[3];
  const float* b2 = (const float*)d_in[4];
  const float* w3 = (const float*)d_in[5];
  const float* b3 = (const float*)d_in[6];
  const float* w4 = (const float*)d_in[7];
  const float* b4 = (const float*)d_in[8];
  const float* a_wqk[4] = {(const float*)d_in[9],  (const float*)d_in[12], (const float*)d_in[15], (const float*)d_in[18]};
  const float* a_wt[4]  = {(const float*)d_in[10], (const float*)d_in[13], (const float*)d_in[16], (const float*)d_in[19]};
  const float* a_bt[4]  = {(const float*)d_in[11], (const float*)d_in[14], (const float*)d_in[17], (const float*)d_in[20]};
  int a_D[4] = {in_sizes[9], in_sizes[12], in_sizes[15], in_sizes[18]};
  const float* f1mw = (const float*)d_in[21]; const float* f1mb = (const float*)d_in[22];
  const float* f2mw = (const float*)d_in[23]; const float* f2mb = (const float*)d_in[24];
  const float* f3mw = (const float*)d_in[25]; const float* f3mb = (const float*)d_in[26];
  const float* f1vw = (const float*)d_in[27]; const float* f1vb = (const float*)d_in[28];
  const float* f2vw = (const float*)d_in[29]; const float* f2vb = (const float*)d_in[30];
  const float* f3vw = (const float*)d_in[31]; const float* f3vb = (const float*)d_in[32];
  float* out = (float*)d_out;

  float* ws = (float*)d_ws;
  float* xn     = ws; ws += (size_t)NB * NP * 3;
  float* dens   = ws; ws += NB * NP;
  float* maxinv = ws; ws += 16;
  float* coef   = ws; ws += 16;
  float* rinv   = ws; ws += NB * NP;
  float* cinv   = ws; ws += NB * NP;
  float* g      = ws; ws += NB * 512;
  float* Hb     = ws; ws += (size_t)NB * 512 * NP;
  float* Ub     = ws; ws += (size_t)NB * 512 * NP;
  float* Tb     = ws; ws += (size_t)NB * 512 * NP;

  k_prep<<<NB * NP / 256, 256, 0, stream>>>(x, xn, Ub);   // Ub temporarily holds x^T [B,3,N]
  k_zero1<<<1, 64, 0, stream>>>(maxinv);
  k_density<<<NB * NP / 8, 512, 0, stream>>>(xn, dens, (int*)maxinv);
  k_scale<<<NB * NP / 256, 256, 0, stream>>>(dens, maxinv);

  auto conv = [&](const float* W, const float* bias, const float* IN, int Cin, int Cout, bool relu) {
    if (Cin < 64)
      k_gemm<<<dim3(NP / 64, Cout / 64, NB), 256, 0, stream>>>(W, IN, bias, Tb, Cin, Cout);
    else
      k_gemm_mfma<<<dim3(NP / 128, Cout / 128, NB), 256, 0, stream>>>(W, IN, bias, Tb, Cin, Cout);
    k_bn<<<Cout, 256, 0, stream>>>(Tb, Hb, Cout, relu ? 1 : 0, 0);
  };
  auto attn = [&](int li, int C) {
    k_coef<<<1, 64, 0, stream>>>(a_wqk[li], a_D[li], coef);
    k_attn_small<<<NB, 256, 0, stream>>>(dens, coef, rinv, cinv);
    k_xrP<<<dim3(C, NB), 256, 0, stream>>>(Hb, Ub, dens, rinv, cinv, coef, C);
    k_gemm_mfma<<<dim3(NP / 128, C / 128, NB), 256, 0, stream>>>(a_wt[li], Ub, a_bt[li], Tb, C, C);
    k_bn<<<C, 256, 0, stream>>>(Tb, Hb, C, 1, 1);
  };

  conv(w1, b1, Ub, 3, 128, true);
  attn(0, 128);
  conv(w2, b2, Hb, 128, 128, true);
  attn(1, 128);
  conv(w3, b3, Hb, 128, 256, true);
  attn(2, 256);
  conv(w4, b4, Hb, 256, 512, false);
  attn(3, 512);

  k_maxpool<<<NB * 512, 64, 0, stream>>>(Hb, g);
  k_head<<<2, 256, 0, stream>>>(g, f1mw, f1mb, f2mw, f2mb, f3mw, f3mb,
                                f1vw, f1vb, f2vw, f2vb, f3vw, f3vb, out);
}

// Round 14
// 467.792 us; speedup vs baseline: 1.2235x; 1.2235x over previous
//
#include <hip/hip_runtime.h>
#include <cfloat>
#include <cmath>

constexpr int NB = 8;
constexpr int NP = 2048;
constexpr int NK = 11;   // Taylor terms k=0..10; err <= s^11/11! (s ~ 0.3) ~ 1e-11

typedef __attribute__((ext_vector_type(4))) float f32x4;
typedef __attribute__((ext_vector_type(8))) short bf16x8;
#define MFMA16(a, b, c) __builtin_amdgcn_mfma_f32_16x16x32_bf16(a, b, c, 0, 0, 0)

__device__ inline ushort f2bf(float f) {   // round-to-nearest-even f32 -> bf16
  union { float f; unsigned u; } v; v.f = f;
  unsigned r = v.u + 0x7FFFu + ((v.u >> 16) & 1u);
  return (ushort)(r >> 16);
}
__device__ inline unsigned pk2bf(float a, float b) {
  return (unsigned)f2bf(a) | ((unsigned)f2bf(b) << 16);
}

// Per-32-lane-half sum: after row_shr 1/2/4/8 + row_bcast:15, lane31 holds
// sum(lanes 0..31), lane63 holds sum(lanes 32..63).
__device__ inline int dpp_half_sum_i32(int c) {
  c += __builtin_amdgcn_update_dpp(0, c, 0x111, 0xf, 0xf, true);  // row_shr:1
  c += __builtin_amdgcn_update_dpp(0, c, 0x112, 0xf, 0xf, true);  // row_shr:2
  c += __builtin_amdgcn_update_dpp(0, c, 0x114, 0xf, 0xf, true);  // row_shr:4
  c += __builtin_amdgcn_update_dpp(0, c, 0x118, 0xf, 0xf, true);  // row_shr:8
  c += __builtin_amdgcn_update_dpp(0, c, 0x142, 0xf, 0xf, true);  // row_bcast:15
  return c;
}

// ---------- prep: normalize x -> xn ; transpose x -> xt [B,3,N] ----------
__global__ void k_prep(const float* __restrict__ x, float* __restrict__ xn, float* __restrict__ xt) {
  int i = blockIdx.x * blockDim.x + threadIdx.x;
  if (i >= NB * NP) return;
  int b = i >> 11, n = i & (NP - 1);
  float a0 = x[i * 3 + 0], a1 = x[i * 3 + 1], a2 = x[i * 3 + 2];
  float rn = rsqrtf(a0 * a0 + a1 * a1 + a2 * a2);
  xn[i * 3 + 0] = a0 * rn; xn[i * 3 + 1] = a1 * rn; xn[i * 3 + 2] = a2 * rn;
  float* xb = xt + (size_t)b * 3 * NP;
  xb[0 * NP + n] = a0; xb[1 * NP + n] = a1; xb[2 * NP + n] = a2;
}

__global__ void k_zero1(float* p) { if (threadIdx.x == 0) p[0] = 0.f; }

// ---------- density: R10 structure (2 rows/wave, d[64]) with quaternary search ----
// 7 quaternary passes (3 thresholds, counts packed 2-per-int) + 1 binary pass
// = 15 binary-equivalent precision at 8/18 of the per-pass array traffic
// (R10's 18-pass variant measured 116us; traffic scales with pass count).
__global__ __launch_bounds__(512, 1) void k_density(const float* __restrict__ xn,
                                                    float* __restrict__ inv,
                                                    int* __restrict__ maxinv) {
  __shared__ float sx[NP], sy[NP], sz[NP];
  int t = threadIdx.x;
  int w = t >> 6, lane = t & 63, half = lane >> 5, sl = lane & 31;
  int row0 = blockIdx.x * 16;
  int b = row0 >> 11;                       // 128 blocks per batch
  const float4* xb4 = (const float4*)(xn + (size_t)b * NP * 3);
  {  // thread t stages points 4t..4t+3 (3 coalesced float4 loads)
    float4 a = xb4[t * 3 + 0], c4 = xb4[t * 3 + 1], e4 = xb4[t * 3 + 2];
    int p = t * 4;
    sx[p + 0] = a.x;  sy[p + 0] = a.y;  sz[p + 0] = a.z;
    sx[p + 1] = a.w;  sy[p + 1] = c4.x; sz[p + 1] = c4.y;
    sx[p + 2] = c4.z; sy[p + 2] = c4.w; sz[p + 2] = e4.x;
    sx[p + 3] = e4.y; sy[p + 3] = e4.z; sz[p + 3] = e4.w;
  }
  __syncthreads();
  int row = row0 + w * 2 + half;
  int n = row & (NP - 1);
  float px = sx[n], py = sy[n], pz = sz[n];
  float d[64];
  float mn = FLT_MAX, mx = -FLT_MAX;
  #pragma unroll
  for (int k = 0; k < 64; ++k) {
    int m = sl + (k << 5);                  // 32 consecutive addrs per half
    float v = 1.0f - (px * sx[m] + py * sy[m] + pz * sz[m]);
    d[k] = v;
    mn = fminf(mn, v); mx = fmaxf(mx, v);
  }
  // per-half bounds: mn = row min; mx = min over lanes of per-lane max
  #pragma unroll
  for (int off = 16; off; off >>= 1) {      // xor offsets 1..16 stay in half
    mn = fminf(mn, __shfl_xor(mn, off));
    mx = fminf(mx, __shfl_xor(mx, off));
  }
  float lo = mn, hi = mx + 1e-6f;
  int baddr = (half ? 63 : 31) << 2;        // bpermute source lane
  for (int it = 0; it < 7; ++it) {          // quaternary passes
    float dd = hi - lo;
    float t1 = lo + 0.25f * dd, t2 = lo + 0.5f * dd, t3 = lo + 0.75f * dd;
    int c12 = 0, c3 = 0;
    #pragma unroll
    for (int k = 0; k < 64; ++k) {
      float v = d[k];
      c12 += (v < t1 ? 1 : 0) + (v < t2 ? 65536 : 0);
      c3  += (v < t3 ? 1 : 0);
    }
    c12 = dpp_half_sum_i32(c12);
    c3  = dpp_half_sum_i32(c3);
    c12 = __builtin_amdgcn_ds_bpermute(baddr, c12);
    c3  = __builtin_amdgcn_ds_bpermute(baddr, c3);
    int c1 = c12 & 0xFFFF, c2 = (int)(((unsigned)c12) >> 16);
    bool le3 = c3 <= 32, le2 = c2 <= 32, le1 = c1 <= 32;
    float nlo = le3 ? t3 : (le2 ? t2 : (le1 ? t1 : lo));
    float nhi = le3 ? hi : (le2 ? t3 : (le1 ? t2 : t1));
    lo = nlo; hi = nhi;                     // invariant: cnt(<lo)<=32<cnt(<hi)
  }
  {                                         // one binary refinement pass
    float tt = 0.5f * (lo + hi);
    int c = 0;
    #pragma unroll
    for (int k = 0; k < 64; ++k) c += (d[k] < tt) ? 1 : 0;
    c = dpp_half_sum_i32(c);
    c = __builtin_amdgcn_ds_bpermute(baddr, c);
    bool le = c <= 32;
    lo = le ? tt : lo;
  }
  float s = 0.f; int c = 0;
  #pragma unroll
  for (int k = 0; k < 64; ++k) {
    bool p = d[k] < lo;
    s += p ? d[k] : 0.f;
    c += p ? 1 : 0;
  }
  c = dpp_half_sum_i32(c);
  int ctot = __builtin_amdgcn_ds_bpermute(baddr, c);
  #pragma unroll
  for (int off = 16; off; off >>= 1) s += __shfl_xor(s, off);
  float sum = s + (float)(32 - ctot) * lo;  // pad remaining picks at threshold
  if (sl == 0) {
    float iv = 32.0f / sum;
    inv[row] = iv;
    atomicMax(maxinv, __float_as_int(iv));
  }
}

__global__ void k_scale(float* __restrict__ dens, const float* __restrict__ maxinv) {
  int i = blockIdx.x * 256 + threadIdx.x;
  if (i < NB * NP) dens[i] *= (1.0f / maxinv[0]);
}

// ---------- per-batch: coef (local) + S_k -> rinv -> T_k -> cinv ----------
// coef computed redundantly per wave (wqk is <=128 floats); block 0 publishes
// coef to global for k_xrP. Eliminates the separate k_coef launch.
__global__ __launch_bounds__(256) void k_attn_small(const float* __restrict__ dens,
                                                    const float* __restrict__ wqk, int D,
                                                    float* __restrict__ coef_out,
                                                    float* __restrict__ rinv,
                                                    float* __restrict__ cinv) {
  int b = blockIdx.x, t = threadIdx.x, w = t >> 6, lane = t & 63;
  // s = sum(wqk^2), per-wave redundant
  float sv = 0.f;
  for (int i = lane; i < D; i += 64) sv += wqk[i] * wqk[i];
  #pragma unroll
  for (int off = 32; off; off >>= 1) sv += __shfl_xor(sv, off);
  float coef[NK];
  coef[0] = 1.f;
  {
    float cc = 1.f;
    #pragma unroll
    for (int k = 1; k < NK; ++k) { cc *= sv / (float)k; coef[k] = cc; }
  }
  if (b == 0 && t == 0) {
    for (int k = 0; k < NK; ++k) coef_out[k] = coef[k];
  }
  const float* db = dens + b * NP;
  float d[8], r[8];
  *(float4*)&d[0] = *(const float4*)(db + t * 8);
  *(float4*)&d[4] = *(const float4*)(db + t * 8 + 4);
  __shared__ float part[NK][4];
  float q[NK];
  // S_k = sum d^k
  {
    float acc[NK];
    #pragma unroll
    for (int k = 0; k < NK; ++k) acc[k] = 0.f;
    #pragma unroll
    for (int e = 0; e < 8; ++e) {
      float p = 1.f;
      #pragma unroll
      for (int k = 0; k < NK; ++k) { acc[k] += p; p *= d[e]; }
    }
    #pragma unroll
    for (int k = 0; k < NK; ++k) {
      float a = acc[k];
      #pragma unroll
      for (int off = 32; off; off >>= 1) a += __shfl_xor(a, off);
      if (lane == 0) part[k][w] = a;
    }
    __syncthreads();
    #pragma unroll
    for (int k = 0; k < NK; ++k)
      q[k] = coef[k] * ((part[k][0] + part[k][1]) + (part[k][2] + part[k][3]));
    __syncthreads();
  }
  // rinv[n] = 1 / sum_k q_k d^k
  #pragma unroll
  for (int e = 0; e < 8; ++e) {
    float poly = q[NK - 1];
    #pragma unroll
    for (int k = NK - 2; k >= 0; --k) poly = poly * d[e] + q[k];
    r[e] = 1.0f / poly;
  }
  *(float4*)(rinv + b * NP + t * 8)     = *(float4*)&r[0];
  *(float4*)(rinv + b * NP + t * 8 + 4) = *(float4*)&r[4];
  // T_k = sum rinv d^k
  {
    float acc[NK];
    #pragma unroll
    for (int k = 0; k < NK; ++k) acc[k] = 0.f;
    #pragma unroll
    for (int e = 0; e < 8; ++e) {
      float p = r[e];
      #pragma unroll
      for (int k = 0; k < NK; ++k) { acc[k] += p; p *= d[e]; }
    }
    #pragma unroll
    for (int k = 0; k < NK; ++k) {
      float a = acc[k];
      #pragma unroll
      for (int off = 32; off; off >>= 1) a += __shfl_xor(a, off);
      if (lane == 0) part[k][w] = a;
    }
    __syncthreads();
    #pragma unroll
    for (int k = 0; k < NK; ++k)
      q[k] = coef[k] * ((part[k][0] + part[k][1]) + (part[k][2] + part[k][3]));
  }
  // cinv[m] = 1 / (1e-9 + sum_k q_k d^k)
  #pragma unroll
  for (int e = 0; e < 8; ++e) {
    float poly = q[NK - 1];
    #pragma unroll
    for (int k = NK - 2; k >= 0; --k) poly = poly * d[e] + q[k];
    r[e] = 1.0f / (poly + 1e-9f);
  }
  *(float4*)(cinv + b * NP + t * 8)     = *(float4*)&r[0];
  *(float4*)(cinv + b * NP + t * 8 + 4) = *(float4*)&r[4];
}

// ---------- fused x_r: one block per (b,c) row ----------
// P_k = sum_n H[c][n] rinv[n] d^k ; U[c][m] = H[c][m] - cinv[m]*sum_k coef_k P_k d^k
__global__ __launch_bounds__(256) void k_xrP(const float* __restrict__ H, float* __restrict__ U,
                                             const float* __restrict__ dens,
                                             const float* __restrict__ rinv,
                                             const float* __restrict__ cinv,
                                             const float* __restrict__ coef, int C) {
  int b = blockIdx.y, c = blockIdx.x, t = threadIdx.x, w = t >> 6, lane = t & 63;
  const float* Hc = H + ((size_t)b * C + c) * NP;
  float* Uc = U + ((size_t)b * C + c) * NP;
  const float* db = dens + b * NP;
  const float* rb = rinv + b * NP;
  const float* cb = cinv + b * NP;
  float h[8], d[8], r[8], cv[8];
  *(float4*)&h[0] = *(const float4*)(Hc + t * 8);
  *(float4*)&h[4] = *(const float4*)(Hc + t * 8 + 4);
  *(float4*)&d[0] = *(const float4*)(db + t * 8);
  *(float4*)&d[4] = *(const float4*)(db + t * 8 + 4);
  *(float4*)&r[0] = *(const float4*)(rb + t * 8);
  *(float4*)&r[4] = *(const float4*)(rb + t * 8 + 4);
  *(float4*)&cv[0] = *(const float4*)(cb + t * 8);
  *(float4*)&cv[4] = *(const float4*)(cb + t * 8 + 4);
  float acc[NK];
  #pragma unroll
  for (int k = 0; k < NK; ++k) acc[k] = 0.f;
  #pragma unroll
  for (int e = 0; e < 8; ++e) {
    float p = h[e] * r[e];
    #pragma unroll
    for (int k = 0; k < NK; ++k) { acc[k] += p; p *= d[e]; }
  }
  __shared__ float part[NK][4];
  #pragma unroll
  for (int k = 0; k < NK; ++k) {
    float a = acc[k];
    #pragma unroll
    for (int off = 32; off; off >>= 1) a += __shfl_xor(a, off);
    if (lane == 0) part[k][w] = a;
  }
  __syncthreads();
  float q[NK];
  #pragma unroll
  for (int k = 0; k < NK; ++k)
    q[k] = coef[k] * ((part[k][0] + part[k][1]) + (part[k][2] + part[k][3]));
  float u[8];
  #pragma unroll
  for (int e = 0; e < 8; ++e) {
    float poly = q[NK - 1];
    #pragma unroll
    for (int k = NK - 2; k >= 0; --k) poly = poly * d[e] + q[k];
    u[e] = h[e] - cv[e] * poly;
  }
  *(float4*)(Uc + t * 8)     = *(float4*)&u[0];
  *(float4*)(Uc + t * 8 + 4) = *(float4*)&u[4];
}

// ---------- conv1x1 via bf16 MFMA ----------
constexpr int LDA = 72;  // bf16 units per LDS row (64 + 8 pad)

__global__ __launch_bounds__(256) void k_gemm_mfma(const float* __restrict__ W,
                                                   const float* __restrict__ IN,
                                                   const float* __restrict__ bias,
                                                   float* __restrict__ OUT,
                                                   int Cin, int Cout) {
  int b = blockIdx.z, n0 = blockIdx.x * 128, o0 = blockIdx.y * 128;
  int tid = threadIdx.x, lane = tid & 63, w = tid >> 6;
  int wr = w >> 1, wc = w & 1;
  const float* Ib = IN + (size_t)b * Cin * NP;
  float* Ob = OUT + (size_t)b * Cout * NP;
  __shared__ ushort Asm[128 * LDA];
  __shared__ ushort Bsm[128 * LDA];
  f32x4 acc[4][4];
  #pragma unroll
  for (int i = 0; i < 4; ++i)
    #pragma unroll
    for (int j = 0; j < 4; ++j) acc[i][j] = (f32x4)(0.0f);

  int row = tid >> 1, half = tid & 1;
  int csub = tid & 63, q = tid >> 6;
  for (int cc0 = 0; cc0 < Cin; cc0 += 64) {
    __syncthreads();
    {   // A: rows=o (128), cols=c' (64) from W
      const float* src = W + (size_t)(o0 + row) * Cin + cc0 + half * 32;
      unsigned* dst = (unsigned*)(Asm + row * LDA + half * 32);
      #pragma unroll
      for (int i = 0; i < 8; ++i) {
        float4 v = *(const float4*)(src + i * 4);
        dst[i * 2 + 0] = pk2bf(v.x, v.y);
        dst[i * 2 + 1] = pk2bf(v.z, v.w);
      }
      // B: rows=n' (128), cols=c' (64) — transpose of IN[c][n]
      const float* isrc = Ib + (size_t)(cc0 + csub) * NP + n0 + q * 32;
      #pragma unroll
      for (int i = 0; i < 8; ++i) {
        float4 v = *(const float4*)(isrc + i * 4);
        ushort* bd = Bsm + (q * 32 + i * 4) * LDA + csub;
        bd[0]       = f2bf(v.x);
        bd[LDA]     = f2bf(v.y);
        bd[2 * LDA] = f2bf(v.z);
        bd[3 * LDA] = f2bf(v.w);
      }
    }
    __syncthreads();
    #pragma unroll
    for (int kk = 0; kk < 64; kk += 32) {
      bf16x8 af[4], bfr[4];
      #pragma unroll
      for (int i = 0; i < 4; ++i) {
        af[i]  = *(const bf16x8*)(Asm + (wr * 64 + i * 16 + (lane & 15)) * LDA + kk + (lane >> 4) * 8);
        bfr[i] = *(const bf16x8*)(Bsm + (wc * 64 + i * 16 + (lane & 15)) * LDA + kk + (lane >> 4) * 8);
      }
      #pragma unroll
      for (int i = 0; i < 4; ++i)
        #pragma unroll
        for (int j = 0; j < 4; ++j)
          acc[i][j] = MFMA16(af[i], bfr[j], acc[i][j]);
    }
  }
  #pragma unroll
  for (int i = 0; i < 4; ++i) {
    #pragma unroll
    for (int r = 0; r < 4; ++r) {
      int o = o0 + wr * 64 + i * 16 + (lane >> 4) * 4 + r;
      float bv = bias[o];
      #pragma unroll
      for (int j = 0; j < 4; ++j) {
        int n = n0 + wc * 64 + j * 16 + (lane & 15);
        Ob[(size_t)o * NP + n] = acc[i][j][r] + bv;
      }
    }
  }
}

// ---------- fp32 GEMM (conv1 only, Cin=3) ----------
__global__ __launch_bounds__(256) void k_gemm(const float* __restrict__ W,
                                              const float* __restrict__ IN,
                                              const float* __restrict__ bias,
                                              float* __restrict__ OUT,
                                              int Cin, int Cout) {
  int b = blockIdx.z;
  int n0 = blockIdx.x * 64;
  int o0 = blockIdx.y * 64;
  int tid = threadIdx.x;
  int tx = tid & 15, ty = tid >> 4;
  const float* Ib = IN + (size_t)b * Cin * NP;
  float* Ob = OUT + (size_t)b * Cout * NP;
  __shared__ float Wt[64][65];
  __shared__ float It[64][65];
  float acc[4][4] = {};
  for (int c0 = 0; c0 < Cin; c0 += 64) {
    __syncthreads();
    {
      int ci = tid & 63, ob4 = tid >> 6;
      bool cv = (c0 + ci) < Cin;
      #pragma unroll
      for (int k = 0; k < 16; ++k) {
        int oi = ob4 + (k << 2);
        Wt[ci][oi] = cv ? W[(size_t)(o0 + oi) * Cin + c0 + ci] : 0.f;
      }
      int ni = tid & 63, cb4 = tid >> 6;
      #pragma unroll
      for (int k = 0; k < 16; ++k) {
        int ci2 = cb4 + (k << 2);
        It[ci2][ni] = (c0 + ci2) < Cin ? Ib[(size_t)(c0 + ci2) * NP + n0 + ni] : 0.f;
      }
    }
    __syncthreads();
    #pragma unroll 4
    for (int ci = 0; ci < 64; ++ci) {
      float a0 = Wt[ci][ty * 4 + 0], a1 = Wt[ci][ty * 4 + 1], a2 = Wt[ci][ty * 4 + 2], a3 = Wt[ci][ty * 4 + 3];
      float b0 = It[ci][tx * 4 + 0], b1 = It[ci][tx * 4 + 1], b2 = It[ci][tx * 4 + 2], b3 = It[ci][tx * 4 + 3];
      acc[0][0] += a0 * b0; acc[0][1] += a0 * b1; acc[0][2] += a0 * b2; acc[0][3] += a0 * b3;
      acc[1][0] += a1 * b0; acc[1][1] += a1 * b1; acc[1][2] += a1 * b2; acc[1][3] += a1 * b3;
      acc[2][0] += a2 * b0; acc[2][1] += a2 * b1; acc[2][2] += a2 * b2; acc[2][3] += a2 * b3;
      acc[3][0] += a3 * b0; acc[3][1] += a3 * b1; acc[3][2] += a3 * b2; acc[3][3] += a3 * b3;
    }
  }
  #pragma unroll
  for (int i = 0; i < 4; ++i) {
    int o = o0 + ty * 4 + i;
    float bv = bias[o];
    #pragma unroll
    for (int j = 0; j < 4; ++j) {
      int n = n0 + tx * 4 + j;
      Ob[(size_t)o * NP + n] = acc[i][j] + bv;
    }
  }
}

// ---------- fused BN: stats + apply (+optional fused global max pool) ----------
__global__ __launch_bounds__(256) void k_bn(const float* __restrict__ T, float* __restrict__ H,
                                            int C, int relu, int acc, int pool,
                                            float* __restrict__ gout) {
  int c = blockIdx.x, t = threadIdx.x, w = t >> 6, lane = t & 63;
  float4 v[16];
  float s = 0.f, s2 = 0.f;
  #pragma unroll
  for (int b = 0; b < NB; ++b) {
    const float4* p = (const float4*)(T + ((size_t)b * C + c) * NP);
    #pragma unroll
    for (int i = 0; i < 2; ++i) {
      float4 x = p[t + i * 256];
      v[b * 2 + i] = x;
      s += (x.x + x.y) + (x.z + x.w);
      s2 += (x.x * x.x + x.y * x.y) + (x.z * x.z + x.w * x.w);
    }
  }
  #pragma unroll
  for (int off = 32; off; off >>= 1) { s += __shfl_xor(s, off); s2 += __shfl_xor(s2, off); }
  __shared__ float ps[4], ps2[4];
  if (lane == 0) { ps[w] = s; ps2[w] = s2; }
  __syncthreads();
  float ts = (ps[0] + ps[1]) + (ps[2] + ps[3]);
  float ts2 = (ps2[0] + ps2[1]) + (ps2[2] + ps2[3]);
  float m = ts * (1.0f / (NB * NP));
  float var = ts2 * (1.0f / (NB * NP)) - m * m;
  float is = rsqrtf(var + 1e-5f);
  float bmax[NB];
  #pragma unroll
  for (int b = 0; b < NB; ++b) bmax[b] = -FLT_MAX;
  #pragma unroll
  for (int b = 0; b < NB; ++b) {
    float4* hp = (float4*)(H + ((size_t)b * C + c) * NP);
    #pragma unroll
    for (int i = 0; i < 2; ++i) {
      float4 x = v[b * 2 + i];
      x.x = (x.x - m) * is; x.y = (x.y - m) * is; x.z = (x.z - m) * is; x.w = (x.w - m) * is;
      if (relu) {
        x.x = fmaxf(x.x, 0.f); x.y = fmaxf(x.y, 0.f); x.z = fmaxf(x.z, 0.f); x.w = fmaxf(x.w, 0.f);
      }
      if (acc) {
        float4 h = hp[t + i * 256];
        x.x += h.x; x.y += h.y; x.z += h.z; x.w += h.w;
      }
      hp[t + i * 256] = x;
      if (pool) bmax[b] = fmaxf(bmax[b], fmaxf(fmaxf(x.x, x.y), fmaxf(x.z, x.w)));
    }
  }
  if (pool) {
    __shared__ float pm[4][NB];
    #pragma unroll
    for (int b = 0; b < NB; ++b) {
      float m2 = bmax[b];
      #pragma unroll
      for (int off = 32; off; off >>= 1) m2 = fmaxf(m2, __shfl_xor(m2, off));
      if (lane == 0) pm[w][b] = m2;
    }
    __syncthreads();
    if (t < NB) {
      float m2 = fmaxf(fmaxf(pm[0][t], pm[1][t]), fmaxf(pm[2][t], pm[3][t]));
      gout[t * C + c] = m2;
    }
  }
}

// ---------- MLP head ----------
__global__ __launch_bounds__(256) void k_head(const float* __restrict__ g,
    const float* __restrict__ f1mw, const float* __restrict__ f1mb,
    const float* __restrict__ f2mw, const float* __restrict__ f2mb,
    const float* __restrict__ f3mw, const float* __restrict__ f3mb,
    const float* __restrict__ f1vw, const float* __restrict__ f1vb,
    const float* __restrict__ f2vw, const float* __restrict__ f2vb,
    const float* __restrict__ f3vw, const float* __restrict__ f3vb,
    float* __restrict__ out) {
  bool vpath = (blockIdx.x == 1);
  const float* w1 = vpath ? f1vw : f1mw;
  const float* c1 = vpath ? f1vb : f1mb;
  const float* w2 = vpath ? f2vw : f2mw;
  const float* c2 = vpath ? f2vb : f2mb;
  __shared__ float gg[NB * 512];
  __shared__ float a1[NB * 256];
  __shared__ float a2[NB * 128];
  __shared__ float zz[NB * 128];
  __shared__ float nrm[NB];
  int t = threadIdx.x;
  for (int i = t; i < NB * 512; i += 256) gg[i] = g[i];
  __syncthreads();
  float o[NB];
  {
    #pragma unroll
    for (int b = 0; b < NB; ++b) o[b] = c1[t];
    const float* wr = w1 + (size_t)t * 512;
    for (int j = 0; j < 512; ++j) {
      float w = wr[j];
      #pragma unroll
      for (int b = 0; b < NB; ++b) o[b] += gg[b * 512 + j] * w;
    }
    float mean = 0.f;
    #pragma unroll
    for (int b = 0; b < NB; ++b) mean += o[b];
    mean *= (1.0f / NB);
    float var = 0.f;
    #pragma unroll
    for (int b = 0; b < NB; ++b) { float d = o[b] - mean; var += d * d; }
    var *= (1.0f / NB);
    float is = rsqrtf(var + 1e-5f);
    #pragma unroll
    for (int b = 0; b < NB; ++b) a1[b * 256 + t] = fmaxf((o[b] - mean) * is, 0.f);
  }
  __syncthreads();
  if (t < 128) {
    #pragma unroll
    for (int b = 0; b < NB; ++b) o[b] = c2[t];
    const float* wr = w2 + (size_t)t * 256;
    for (int j = 0; j < 256; ++j) {
      float w = wr[j];
      #pragma unroll
      for (int b = 0; b < NB; ++b) o[b] += a1[b * 256 + j] * w;
    }
    float mean = 0.f;
    #pragma unroll
    for (int b = 0; b < NB; ++b) mean += o[b];
    mean *= (1.0f / NB);
    float var = 0.f;
    #pragma unroll
    for (int b = 0; b < NB; ++b) { float d = o[b] - mean; var += d * d; }
    var *= (1.0f / NB);
    float is = rsqrtf(var + 1e-5f);
    #pragma unroll
    for (int b = 0; b < NB; ++b) a2[b * 128 + t] = fmaxf((o[b] - mean) * is, 0.f);
  }
  __syncthreads();
  if (!vpath) {
    if (t < 128) {
      const float* wr = f3mw + (size_t)t * 128;
      for (int b = 0; b < NB; ++b) {
        float s = f3mb[t];
        for (int j = 0; j < 128; ++j) s += a2[b * 128 + j] * wr[j];
        zz[b * 128 + t] = s;
      }
    }
    __syncthreads();
    if (t < NB) {
      float s = 0.f;
      for (int j = 0; j < 128; ++j) { float v = zz[t * 128 + j]; s += v * v; }
      nrm[t] = sqrtf(s);
    }
    __syncthreads();
    if (t < 128) {
      for (int b = 0; b < NB; ++b) out[b * 128 + t] = zz[b * 128 + t] / nrm[b];
    }
  } else {
    if (t < NB) {
      float s = f3vb[0];
      for (int j = 0; j < 128; ++j) s += a2[t * 128 + j] * f3vw[j];
      float sp = (s > 20.f) ? s : log1pf(expf(s));
      out[NB * 128 + t] = sp + 1.0f;
    }
  }
}

extern "C" void kernel_launch(void* const* d_in, const int* in_sizes, int n_in,
                              void* d_out, int out_size, void* d_ws, size_t ws_size,
                              hipStream_t stream) {
  const float* x  = (const float*)d_in[0];
  const float* w1 = (const float*)d_in[1];
  const float* b1 = (const float*)d_in[2];
  const float* w2 = (const float*)d_in[3];
  const float* b2 = (const float*)d_in[4];
  const float* w3 = (const float*)d_in[5];
  const float* b3 = (const float*)d_in[6];
  const float* w4 = (const float*)d_in[7];
  const float* b4 = (const float*)d_in[8];
  const float* a_wqk[4] = {(const float*)d_in[9],  (const float*)d_in[12], (const float*)d_in[15], (const float*)d_in[18]};
  const float* a_wt[4]  = {(const float*)d_in[10], (const float*)d_in[13], (const float*)d_in[16], (const float*)d_in[19]};
  const float* a_bt[4]  = {(const float*)d_in[11], (const float*)d_in[14], (const float*)d_in[17], (const float*)d_in[20]};
  int a_D[4] = {in_sizes[9], in_sizes[12], in_sizes[15], in_sizes[18]};
  const float* f1mw = (const float*)d_in[21]; const float* f1mb = (const float*)d_in[22];
  const float* f2mw = (const float*)d_in[23]; const float* f2mb = (const float*)d_in[24];
  const float* f3mw = (const float*)d_in[25]; const float* f3mb = (const float*)d_in[26];
  const float* f1vw = (const float*)d_in[27]; const float* f1vb = (const float*)d_in[28];
  const float* f2vw = (const float*)d_in[29]; const float* f2vb = (const float*)d_in[30];
  const float* f3vw = (const float*)d_in[31]; const float* f3vb = (const float*)d_in[32];
  float* out = (float*)d_out;

  float* ws = (float*)d_ws;
  float* xn     = ws; ws += (size_t)NB * NP * 3;
  float* dens   = ws; ws += NB * NP;
  float* maxinv = ws; ws += 16;
  float* coef   = ws; ws += 16;
  float* rinv   = ws; ws += NB * NP;
  float* cinv   = ws; ws += NB * NP;
  float* g      = ws; ws += NB * 512;
  float* Hb     = ws; ws += (size_t)NB * 512 * NP;
  float* Ub     = ws; ws += (size_t)NB * 512 * NP;
  float* Tb     = ws; ws += (size_t)NB * 512 * NP;

  k_prep<<<NB * NP / 256, 256, 0, stream>>>(x, xn, Ub);   // Ub temporarily holds x^T [B,3,N]
  k_zero1<<<1, 64, 0, stream>>>(maxinv);
  k_density<<<NB * NP / 16, 512, 0, stream>>>(xn, dens, (int*)maxinv);
  k_scale<<<NB * NP / 256, 256, 0, stream>>>(dens, maxinv);

  auto conv = [&](const float* W, const float* bias, const float* IN, int Cin, int Cout, bool relu) {
    if (Cin < 64)
      k_gemm<<<dim3(NP / 64, Cout / 64, NB), 256, 0, stream>>>(W, IN, bias, Tb, Cin, Cout);
    else
      k_gemm_mfma<<<dim3(NP / 128, Cout / 128, NB), 256, 0, stream>>>(W, IN, bias, Tb, Cin, Cout);
    k_bn<<<Cout, 256, 0, stream>>>(Tb, Hb, Cout, relu ? 1 : 0, 0, 0, g);
  };
  auto attn = [&](int li, int C) {
    k_attn_small<<<NB, 256, 0, stream>>>(dens, a_wqk[li], a_D[li], coef, rinv, cinv);
    k_xrP<<<dim3(C, NB), 256, 0, stream>>>(Hb, Ub, dens, rinv, cinv, coef, C);
    k_gemm_mfma<<<dim3(NP / 128, C / 128, NB), 256, 0, stream>>>(a_wt[li], Ub, a_bt[li], Tb, C, C);
    k_bn<<<C, 256, 0, stream>>>(Tb, Hb, C, 1, 1, (li == 3) ? 1 : 0, g);
  };

  conv(w1, b1, Ub, 3, 128, true);
  attn(0, 128);
  conv(w2, b2, Hb, 128, 128, true);
  attn(1, 128);
  conv(w3, b3, Hb, 128, 256, true);
  attn(2, 256);
  conv(w4, b4, Hb, 256, 512, false);
  attn(3, 512);

  k_head<<<2, 256, 0, stream>>>(g, f1mw, f1mb, f2mw, f2mb, f3mw, f3mb,
                                f1vw, f1vb, f2vw, f2vb, f3vw, f3vb, out);
}